// Round 14
// baseline (822.328 us; speedup 1.0000x reference)
//
#include <hip/hip_runtime.h>
#include <math.h>

// Problem constants (fixed by the reference setup_inputs)
#define BATCH 32
#define CH    192
#define TFEAT 2048
#define TTXT  512
#define NEGINF (-1e9f)

#define ATTN_ELEMS ((size_t)BATCH * TFEAT * TTXT)   // 33,554,432
#define DUR_OFF    ATTN_ELEMS
#define NEG_OFF    (ATTN_ELEMS + (size_t)BATCH * TTXT)

__device__ __forceinline__ void gload_lds16(const float* g, float* l) {
  __builtin_amdgcn_global_load_lds(
      (const __attribute__((address_space(1))) void*)g,
      (__attribute__((address_space(3))) void*)l, 16, 0, 0);
}

#define VMCNT(n) asm volatile("s_waitcnt vmcnt(" #n ")" ::: "memory")

// ---------------------------------------------------------------------------
// Kernel P: W1[b,c,s] = m*exp(-2*logs), W2[b,c,s] = -0.5*exp(-2*logs)
// ---------------------------------------------------------------------------
__global__ void k_prep(const float* __restrict__ m_p,
                       const float* __restrict__ logs_p,
                       float* __restrict__ w1, float* __restrict__ w2) {
  int gid = blockIdx.x * 256 + threadIdx.x;    // 0 .. 3,145,727
  float m = m_p[gid];
  float l = logs_p[gid];
  float r = __expf(-2.0f * l);
  w1[gid] = m * r;
  w2[gid] = -0.5f * r;
}

// ---------------------------------------------------------------------------
// Kernel A: cadd[b][s] = sum_c(-0.5*log(2pi) - logs) + sum_c(-0.5*m^2*r)
// ---------------------------------------------------------------------------
__global__ void k_cadd(const float* __restrict__ m_p,
                       const float* __restrict__ logs_p,
                       float* __restrict__ cadd) {
  int gid = blockIdx.x * 256 + threadIdx.x;        // 0 .. 16383
  int b = gid >> 9, s = gid & (TTXT - 1);
  const float* mp = m_p    + (size_t)b * CH * TTXT + s;
  const float* lp = logs_p + (size_t)b * CH * TTXT + s;
  float acc = -0.5f * 1.8378770664093453f * (float)CH;   // -C/2 * log(2*pi)
  #pragma unroll 4
  for (int c = 0; c < CH; ++c) {
    float l = lp[(size_t)c * TTXT];
    float m = mp[(size_t)c * TTXT];
    float r = __expf(-2.0f * l);
    acc -= l + 0.5f * m * m * r;
  }
  cadd[gid] = acc;
}

// ---------------------------------------------------------------------------
// Kernel B (R14): fp32 GEMM, 256 threads, acc[8][8].
// R13: VALUBusy 54%, LDS pipe the ceiling (384cy LDS vs 256cy VALU per kk
// per CU at acc[8][4]). acc[8][8] doubles FMA per B-byte -> LDS 288 vs VALU
// 256. Half-frag depth-1 pipeline (aA/aB, h0/h1) keeps live ~110 <= 128.
// Per-output-element fma order unchanged (ko asc, kk asc) -> bit-identical.
// Spill tripwire: WRITE_SIZE > 1.4e5 KB => revert to R13 gemm.
// ---------------------------------------------------------------------------
#define BM 128
#define BN 128
#define BK 16

__global__ __launch_bounds__(256)
void k_gemm(const float* __restrict__ z_p,
            const float* __restrict__ w1g, const float* __restrict__ w2g,
            const float* __restrict__ cadd, float* __restrict__ neg) {
  __shared__ float Az[2][BK][BM];
  __shared__ float B1[2][BK][BN];
  __shared__ float B2[2][BK][BN];

  // chunked XCD swizzle (2048 blocks, 8 XCDs, 256 per chunk; bijective)
  int blk = (blockIdx.x & 7) * 256 + (blockIdx.x >> 3);
  int sb = blk & 3;            // TTXT/BN = 4
  int tb = (blk >> 2) & 15;    // TFEAT/BM = 16
  int b  = blk >> 6;
  int tid = threadIdx.x;
  int tx = tid & 15;           // col group: cols tx*4 and 64+tx*4
  int ty = tid >> 4;           // row group: 8 rows at ty*8 (0..15)
  int wid  = tid >> 6;         // wave 0..3
  int lane = tid & 63;
  int lr = lane >> 5;          // row-within-pair
  int lc = (lane & 31) * 4;    // col (float4 granularity)

  const float* zb  = z_p + (size_t)b * CH * TFEAT + (size_t)tb * BM;
  const float* w1b = w1g + (size_t)b * CH * TTXT  + (size_t)sb * BN;
  const float* w2b = w2g + (size_t)b * CH * TTXT  + (size_t)sb * BN;

  auto STAGE = [&](int buf, int ko) {    // wave wid stages rows 4wid..4wid+3
    #pragma unroll
    for (int i = 0; i < 2; ++i) {
      int kr = ko * BK + 4 * wid + 2 * i + lr;   // per-lane global k-row
      int kd = 4 * wid + 2 * i;                  // wave-uniform LDS row base
      gload_lds16(zb  + (size_t)kr * TFEAT + lc, &Az[buf][kd][0]);
      gload_lds16(w1b + (size_t)kr * TTXT  + lc, &B1[buf][kd][0]);
      gload_lds16(w2b + (size_t)kr * TTXT  + lc, &B2[buf][kd][0]);
    }
  };

  float acc[8][8];
  #pragma unroll
  for (int i = 0; i < 8; ++i)
    #pragma unroll
    for (int j = 0; j < 8; ++j) acc[i][j] = 0.0f;

  float aA[8], aB[8];
  float h0p[4], h0q[4], h1p[4], h1q[4];

  auto LOADA = [&](float (&aa)[8], int cur, int kk) {
    float4 a0 = *(const float4*)&Az[cur][kk][ty * 8];
    float4 a1 = *(const float4*)&Az[cur][kk][ty * 8 + 4];
    aa[0]=a0.x; aa[1]=a0.y; aa[2]=a0.z; aa[3]=a0.w;
    aa[4]=a1.x; aa[5]=a1.y; aa[6]=a1.z; aa[7]=a1.w;
  };
  auto LOADH0 = [&](int cur, int kk) {
    float4 p = *(const float4*)&B1[cur][kk][tx * 4];
    float4 q = *(const float4*)&B2[cur][kk][tx * 4];
    h0p[0]=p.x; h0p[1]=p.y; h0p[2]=p.z; h0p[3]=p.w;
    h0q[0]=q.x; h0q[1]=q.y; h0q[2]=q.z; h0q[3]=q.w;
  };
  auto LOADH1 = [&](int cur, int kk) {
    float4 p = *(const float4*)&B1[cur][kk][64 + tx * 4];
    float4 q = *(const float4*)&B2[cur][kk][64 + tx * 4];
    h1p[0]=p.x; h1p[1]=p.y; h1p[2]=p.z; h1p[3]=p.w;
    h1q[0]=q.x; h1q[1]=q.y; h1q[2]=q.z; h1q[3]=q.w;
  };
  auto FMAH0 = [&](const float (&aa)[8]) {
    #pragma unroll
    for (int i = 0; i < 8; ++i)
      #pragma unroll
      for (int j = 0; j < 4; ++j)
        acc[i][j] = fmaf(aa[i], fmaf(aa[i], h0q[j], h0p[j]), acc[i][j]);
  };
  auto FMAH1 = [&](const float (&aa)[8]) {
    #pragma unroll
    for (int i = 0; i < 8; ++i)
      #pragma unroll
      for (int j = 0; j < 4; ++j)
        acc[i][4 + j] = fmaf(aa[i], fmaf(aa[i], h1q[j], h1p[j]), acc[i][4 + j]);
  };

  STAGE(0, 0);
  VMCNT(0);
  __builtin_amdgcn_s_barrier();

  for (int ko = 0; ko < CH / BK; ++ko) {
    int cur = ko & 1;
    if (ko + 1 < CH / BK) STAGE(cur ^ 1, ko + 1);   // prefetch next tile

    LOADA(aA, cur, 0); LOADH0(cur, 0);
    #pragma unroll
    for (int kk = 0; kk < BK; kk += 2) {
      LOADH1(cur, kk);                   // hides under FMAH0(aA)
      FMAH0(aA);
      __builtin_amdgcn_sched_barrier(0);
      LOADA(aB, cur, kk + 1); LOADH0(cur, kk + 1);
      FMAH1(aA);
      __builtin_amdgcn_sched_barrier(0);
      LOADH1(cur, kk + 1);
      FMAH0(aB);
      __builtin_amdgcn_sched_barrier(0);
      if (kk + 2 < BK) { LOADA(aA, cur, kk + 2); LOADH0(cur, kk + 2); }
      FMAH1(aB);
      __builtin_amdgcn_sched_barrier(0);
    }
    VMCNT(0);                            // next tile landed (had whole compute)
    __builtin_amdgcn_s_barrier();
  }

  // epilogue: rows tb*128 + ty*8 + i; cols sb*128 + {tx*4, 64+tx*4}
  const float* cb = cadd + b * TTXT + sb * BN;
  float4 cb0 = *(const float4*)(cb + tx * 4);
  float4 cb1 = *(const float4*)(cb + 64 + tx * 4);
  float c0[4] = {cb0.x, cb0.y, cb0.z, cb0.w};
  float c1[4] = {cb1.x, cb1.y, cb1.z, cb1.w};
  float* ob = neg + (size_t)b * TFEAT * TTXT + (size_t)(tb * BM + ty * 8) * TTXT + sb * BN;
  #pragma unroll
  for (int i = 0; i < 8; ++i) {
    float4 o0 = {acc[i][0] + c0[0], acc[i][1] + c0[1], acc[i][2] + c0[2], acc[i][3] + c0[3]};
    float4 o1 = {acc[i][4] + c1[0], acc[i][5] + c1[1], acc[i][6] + c1[2], acc[i][7] + c1[3]};
    float* row = ob + (size_t)i * TTXT;
    *(float4*)(row + tx * 4)      = o0;
    *(float4*)(row + 64 + tx * 4) = o1;
  }
}

// ---------------------------------------------------------------------------
// Kernel C (R14): skewed-wavefront DP, segment-minimal staging.
// R13 lesson: k_dp cost tracks global-memory SEGMENT count per CU (R12 256
// seg/phase -> 424us; R13 128 gathered -> 290us). R14: each wave stages 4
// fully-CONTIGUOUS 1KB chunks of the window's flat 32KB (chunk k = w + 8c)
// -> 32 segments/phase. Ring is the window flat [16][512]; consumer reads
// its 64-col slice (2-way bank alias = free). Row chain / s_bnd / gbits /
// backtrack verbatim R13 -> bit-exact path.
// ---------------------------------------------------------------------------
#define KROWS 16
#define NWIN  (TFEAT / KROWS)     // 128 windows
#define NMASKW (TTXT / KROWS)     // 32 masked windows

__device__ __forceinline__ float dpp_shr1(float v) {
  return __int_as_float(__builtin_amdgcn_update_dpp(
      __float_as_int(v), __float_as_int(v), 0x138 /*wave_shr:1*/, 0xF, 0xF, false));
}

__global__ __launch_bounds__(512, 1)
void k_dp(const float* __restrict__ neg, float* __restrict__ dur,
          int* __restrict__ idx_out, const float* __restrict__ x_mask,
          unsigned long long* __restrict__ gbits_all) {
  __shared__ float ring[4][KROWS][TTXT];    // 131072 B (window ring, flat)
  __shared__ float bndlds[3][8][KROWS];     //   1536 B (boundary ring)
  int b = blockIdx.x, tid = threadIdx.x;
  int lane = tid & 63, w = tid >> 6;
  const float* nb = neg + (size_t)b * TFEAT * TTXT;
  unsigned long long* gbits = gbits_all + (size_t)b * 8 * TFEAT;  // [8][2048]

  if (tid < 3 * 8 * KROWS) ((float*)bndlds)[tid] = NEGINF;

  auto stage = [&](int j) {               // wave w: 4 contiguous 1KB chunks
    const float* src = nb + (size_t)j * KROWS * TTXT;
    float* dst = &ring[j & 3][0][0];
    #pragma unroll
    for (int c = 0; c < 4; ++c) {
      int k = c * 8 + w;                  // chunk id 0..31
      gload_lds16(src + k * 256 + lane * 4, dst + k * 256);
    }
  };

  stage(0); stage(1); stage(2);
  __syncthreads();                        // drains prologue loads + bndlds init

  float prev = NEGINF;
  for (int p = 0; p < NWIN + 8; ++p) {
    int i = p - w;                        // this wave's window this phase
    if (i >= 0 && i + 3 < NWIN) stage(i + 3);
    VMCNT(12);                            // window i's chunk loads landed
    asm volatile("s_waitcnt lgkmcnt(0)" ::: "memory");
    __builtin_amdgcn_s_barrier();         // bndlds(prev phase) + ring visible
    __builtin_amdgcn_sched_barrier(0);

    if (i >= 0 && i < NWIN) {
      // hoisted boundary values (wave-uniform)
      float s_bnd[KROWS];
      if (w > 0) {
        float v   = bndlds[i % 3][w - 1][lane & 15];
        float v15 = bndlds[(i + 2) % 3][w - 1][15];
        s_bnd[0] = __int_as_float(__builtin_amdgcn_readfirstlane(__float_as_int(v15)));
        #pragma unroll
        for (int r = 1; r < KROWS; ++r)
          s_bnd[r] = __int_as_float(__builtin_amdgcn_readlane(__float_as_int(v), r - 1));
      } else {
        #pragma unroll
        for (int r = 0; r < KROWS; ++r) s_bnd[r] = NEGINF;
        if (i == 0) s_bnd[0] = 0.0f;      // y==0, x==0 edge
      }
      // own-column-slice nf from the flat ring
      float cur[KROWS];
      #pragma unroll
      for (int r = 0; r < KROWS; ++r) cur[r] = ring[i & 3][r][w * 64 + lane];

      int y0 = i * KROWS;
      bool masked = (i < NMASKW);
      unsigned keep_lo = 0, keep_hi = 0;
      float bkeep = 0.0f;
      unsigned long long andm = (w == 0) ? ~1ull : ~0ull;   // x==0 never moves
      #pragma unroll
      for (int r = 0; r < KROWS; ++r) {
        float upd = dpp_shr1(prev);
        float up = (lane == 0) ? s_bnd[r] : upd;
        bool force = masked && (tid == y0 + r);
        bool gt = prev < up;
        unsigned long long m = __ballot(force || gt) & andm;  // uniform
        bool mine = (lane == r);
        keep_lo = mine ? (unsigned)m : keep_lo;
        keep_hi = mine ? (unsigned)(m >> 32) : keep_hi;
        float vc = force ? NEGINF : prev;
        prev = fmaxf(vc, up) + cur[r];
        float v63 = __int_as_float(
            __builtin_amdgcn_readlane(__float_as_int(prev), 63));  // uniform
        bkeep = mine ? v63 : bkeep;
      }
      if (lane < KROWS) {                 // one exec toggle per window
        bndlds[i % 3][w][lane] = bkeep;
        gbits[(size_t)w * TFEAT + y0 + lane] =
            ((unsigned long long)keep_hi << 32) | keep_lo;   // 128B contiguous
      }
    }
  }
  VMCNT(0);
  __syncthreads();                        // gbits stores drained + visible

  // ---- serial backtrack (tid 0), 16-deep register ring over global bits.
  if (tid == 0) {
    const float* xm = x_mask + (size_t)b * TTXT;
    int idx = TTXT - 1, cnt = 0;
    unsigned long long ua[16], ub[16]; int qi[16];
    #pragma unroll
    for (int q16 = 0; q16 < 16; ++q16) {  // rows 2032..2047 (slot = y&15)
      ua[q16] = gbits[(size_t)7 * TFEAT + 2032 + q16];
      ub[q16] = gbits[(size_t)6 * TFEAT + 2032 + q16];
      qi[q16] = 7;
    }
    for (int yb = 2032; yb >= 16; yb -= 16) {
      #pragma unroll
      for (int jj = 15; jj >= 0; --jj) {
        int y = yb + jj;                  // slot = jj (yb % 16 == 0)
        unsigned long long w64 = ((idx >> 6) == qi[jj]) ? ua[jj] : ub[jj];
        idx_out[b * TFEAT + y] = idx;
        cnt++;
        if ((w64 >> (idx & 63)) & 1ull) {
          dur[b * TTXT + idx] = (float)cnt * xm[idx];
          cnt = 0; idx--;
        }
        int q = idx >> 6;                 // refill slot jj for row y-16
        int qm = q > 0 ? q - 1 : 0;
        ua[jj] = gbits[(size_t)q  * TFEAT + (y - 16)];
        ub[jj] = gbits[(size_t)qm * TFEAT + (y - 16)];
        qi[jj] = q;
      }
    }
    #pragma unroll
    for (int jj = 15; jj >= 0; --jj) {    // tail rows 15..0
      int y = jj;
      unsigned long long w64 = ((idx >> 6) == qi[jj]) ? ua[jj] : ub[jj];
      idx_out[b * TFEAT + y] = idx;
      cnt++;
      if ((w64 >> (idx & 63)) & 1ull) {
        dur[b * TTXT + idx] = (float)cnt * xm[idx];
        cnt = 0; idx--;
      }
    }
    dur[b * TTXT] = (float)cnt * xm[0];   // idx == 0 tail run
  }
}

// ---------------------------------------------------------------------------
// Kernel D: attn[b,y,x] = (x == idx[y]) * x_mask[b,x] * y_mask[b,y]
// ---------------------------------------------------------------------------
__global__ void k_attn(const int* __restrict__ idx_arr,
                       const float* __restrict__ x_mask,
                       const float* __restrict__ y_mask,
                       float* __restrict__ attn) {
  size_t gid = (size_t)blockIdx.x * 256 + threadIdx.x;
  size_t e = gid << 2;               // 4 floats per thread
  int b = (int)(e >> 20);            // TFEAT*TTXT = 2^20
  int rem = (int)(e & 1048575u);
  int y = rem >> 9;
  int x0 = rem & 511;
  int idx = idx_arr[b * TFEAT + y];
  float4 v = {0.f, 0.f, 0.f, 0.f};
  int d = idx - x0;
  if (d >= 0 && d < 4) {
    ((float*)&v)[d] = x_mask[b * TTXT + idx] * y_mask[b * TFEAT + y];
  }
  *(float4*)(attn + e) = v;
}

// ---------------------------------------------------------------------------
extern "C" void kernel_launch(void* const* d_in, const int* in_sizes, int n_in,
                              void* d_out, int out_size, void* d_ws, size_t ws_size,
                              hipStream_t stream) {
  const float* z_p    = (const float*)d_in[0];
  const float* m_p    = (const float*)d_in[1];
  const float* logs_p = (const float*)d_in[2];
  const float* x_mask = (const float*)d_in[3];
  const float* y_mask = (const float*)d_in[4];

  float* out  = (float*)d_out;
  float* attn = out;
  float* dur  = out + DUR_OFF;
  float* neg  = out + NEG_OFF;

  // scratch living in the attn region (fully rewritten by k_attn at the end):
  //   w1s/w2s: GEMM weights; gbits: DP decision bits [4 MB]
  float* w1s = attn;
  float* w2s = attn + (size_t)BATCH * CH * TTXT;      // 3,145,728 floats each
  unsigned long long* gbits =
      (unsigned long long*)(attn + 2 * (size_t)BATCH * CH * TTXT);

  // workspace: cadd (64 KiB) + idx array (256 KiB)
  float* cadd = (float*)d_ws;
  int*   idxa = (int*)((char*)d_ws + 65536);

  k_prep<<<(BATCH * CH * TTXT) / 256, 256, 0, stream>>>(m_p, logs_p, w1s, w2s);
  k_cadd<<<(BATCH * TTXT) / 256, 256, 0, stream>>>(m_p, logs_p, cadd);
  k_gemm<<<BATCH * (TFEAT / BM) * (TTXT / BN), 256, 0, stream>>>(z_p, w1s, w2s, cadd, neg);
  k_dp<<<BATCH, 512, 0, stream>>>(neg, dur, idxa, x_mask, gbits);
  k_attn<<<(int)(ATTN_ELEMS / 4 / 256), 256, 0, stream>>>(idxa, x_mask, y_mask, attn);
}

// Round 15
// 744.227 us; speedup vs baseline: 1.1049x; 1.1049x over previous
//
#include <hip/hip_runtime.h>
#include <math.h>

// Problem constants (fixed by the reference setup_inputs)
#define BATCH 32
#define CH    192
#define TFEAT 2048
#define TTXT  512
#define NEGINF (-1e9f)

#define ATTN_ELEMS ((size_t)BATCH * TFEAT * TTXT)   // 33,554,432
#define DUR_OFF    ATTN_ELEMS
#define NEG_OFF    (ATTN_ELEMS + (size_t)BATCH * TTXT)

__device__ __forceinline__ void gload_lds16(const float* g, float* l) {
  __builtin_amdgcn_global_load_lds(
      (const __attribute__((address_space(1))) void*)g,
      (__attribute__((address_space(3))) void*)l, 16, 0, 0);
}
__device__ __forceinline__ void gload_lds16h(const unsigned short* g,
                                             unsigned short* l) {
  __builtin_amdgcn_global_load_lds(
      (const __attribute__((address_space(1))) void*)g,
      (__attribute__((address_space(3))) void*)l, 16, 0, 0);
}

#define VMCNT(n) asm volatile("s_waitcnt vmcnt(" #n ")" ::: "memory")

__device__ __forceinline__ unsigned short f2b16(float f) {   // RNE bf16
  unsigned u = __float_as_uint(f);
  return (unsigned short)((u + 0x7FFFu + ((u >> 16) & 1u)) >> 16);
}

// ---------------------------------------------------------------------------
// Kernel P: W1[b,c,s] = m*exp(-2*logs), W2[b,c,s] = -0.5*exp(-2*logs)
// ---------------------------------------------------------------------------
__global__ void k_prep(const float* __restrict__ m_p,
                       const float* __restrict__ logs_p,
                       float* __restrict__ w1, float* __restrict__ w2) {
  int gid = blockIdx.x * 256 + threadIdx.x;    // 0 .. 3,145,727
  float m = m_p[gid];
  float l = logs_p[gid];
  float r = __expf(-2.0f * l);
  w1[gid] = m * r;
  w2[gid] = -0.5f * r;
}

// ---------------------------------------------------------------------------
// Kernel A: cadd[b][s] = sum_c(-0.5*log(2pi) - logs) + sum_c(-0.5*m^2*r)
// ---------------------------------------------------------------------------
__global__ void k_cadd(const float* __restrict__ m_p,
                       const float* __restrict__ logs_p,
                       float* __restrict__ cadd) {
  int gid = blockIdx.x * 256 + threadIdx.x;        // 0 .. 16383
  int b = gid >> 9, s = gid & (TTXT - 1);
  const float* mp = m_p    + (size_t)b * CH * TTXT + s;
  const float* lp = logs_p + (size_t)b * CH * TTXT + s;
  float acc = -0.5f * 1.8378770664093453f * (float)CH;   // -C/2 * log(2*pi)
  #pragma unroll 4
  for (int c = 0; c < CH; ++c) {
    float l = lp[(size_t)c * TTXT];
    float m = mp[(size_t)c * TTXT];
    float r = __expf(-2.0f * l);
    acc -= l + 0.5f * m * m * r;
  }
  cadd[gid] = acc;
}

// ---------------------------------------------------------------------------
// Kernel B: fp32 GEMM — REVERTED to R13 (512 thr, acc[8][4], Frag depth-1
// pipeline, 2-phase LDS dbuf; 375us, VGPR 116, zero spill). R14's acc[8][8]
// @256thr hit VGPR 188 -> occupancy crash -> 472us. Added: bf16 shadow copy
// negh (RNE) for k_dp's staging (store-only, ~+10us).
// ---------------------------------------------------------------------------
#define BM 128
#define BN 128
#define BK 16

struct Frag { float a[8]; float p[4]; float q[4]; };

__global__ __launch_bounds__(512)
void k_gemm(const float* __restrict__ z_p,
            const float* __restrict__ w1g, const float* __restrict__ w2g,
            const float* __restrict__ cadd, float* __restrict__ neg,
            unsigned short* __restrict__ negh) {
  __shared__ float Az[2][BK][BM];
  __shared__ float B1[2][BK][BN];
  __shared__ float B2[2][BK][BN];

  // chunked XCD swizzle (2048 blocks, 8 XCDs, 256 per chunk; bijective)
  int blk = (blockIdx.x & 7) * 256 + (blockIdx.x >> 3);
  int sb = blk & 3;            // TTXT/BN = 4
  int tb = (blk >> 2) & 15;    // TFEAT/BM = 16
  int b  = blk >> 6;
  int tid = threadIdx.x;
  int tx = tid & 31;           // col group: 4 cols at tx*4
  int ty = tid >> 5;           // row group: 8 rows at ty*8  (0..15)
  int wid  = tid >> 6;         // wave 0..7
  int lane = tid & 63;
  int lr = lane >> 5;          // row-within-pair
  int lc = (lane & 31) * 4;    // col (float4 granularity)

  const float* zb  = z_p + (size_t)b * CH * TFEAT + (size_t)tb * BM;
  const float* w1b = w1g + (size_t)b * CH * TTXT  + (size_t)sb * BN;
  const float* w2b = w2g + (size_t)b * CH * TTXT  + (size_t)sb * BN;

  auto STAGE = [&](int buf, int ko) {
    int kr = ko * BK + 2 * wid + lr;     // per-lane global k-row
    int kd = 2 * wid;                    // wave-uniform LDS row base
    gload_lds16(zb  + (size_t)kr * TFEAT + lc, &Az[buf][kd][0]);
    gload_lds16(w1b + (size_t)kr * TTXT  + lc, &B1[buf][kd][0]);
    gload_lds16(w2b + (size_t)kr * TTXT  + lc, &B2[buf][kd][0]);
  };
  auto LOADF = [&](Frag& f, int cur, int kk) {
    float4 a0 = *(const float4*)&Az[cur][kk][ty * 8];
    float4 a1 = *(const float4*)&Az[cur][kk][ty * 8 + 4];
    float4 p  = *(const float4*)&B1[cur][kk][tx * 4];
    float4 q  = *(const float4*)&B2[cur][kk][tx * 4];
    f.a[0]=a0.x; f.a[1]=a0.y; f.a[2]=a0.z; f.a[3]=a0.w;
    f.a[4]=a1.x; f.a[5]=a1.y; f.a[6]=a1.z; f.a[7]=a1.w;
    f.p[0]=p.x;  f.p[1]=p.y;  f.p[2]=p.z;  f.p[3]=p.w;
    f.q[0]=q.x;  f.q[1]=q.y;  f.q[2]=q.z;  f.q[3]=q.w;
  };

  float acc[8][4];
  #pragma unroll
  for (int i = 0; i < 8; ++i)
    #pragma unroll
    for (int j = 0; j < 4; ++j) acc[i][j] = 0.0f;

  auto FMAF = [&](const Frag& f) {
    #pragma unroll
    for (int i = 0; i < 8; ++i)
      #pragma unroll
      for (int j = 0; j < 4; ++j)
        acc[i][j] = fmaf(f.a[i], fmaf(f.a[i], f.q[j], f.p[j]), acc[i][j]);
  };

  STAGE(0, 0);
  VMCNT(0);
  __builtin_amdgcn_s_barrier();

  for (int ko = 0; ko < CH / BK; ++ko) {
    int cur = ko & 1;
    if (ko + 1 < CH / BK) STAGE(cur ^ 1, ko + 1);   // prefetch next tile

    Frag f0, f1;
    LOADF(f0, cur, 0);
    #pragma unroll
    for (int kk = 0; kk < BK; kk += 2) {
      LOADF(f1, cur, kk + 1);            // reads hide under FMAF(f0)
      FMAF(f0);
      __builtin_amdgcn_sched_barrier(0);
      if (kk + 2 < BK) LOADF(f0, cur, kk + 2);
      FMAF(f1);
      __builtin_amdgcn_sched_barrier(0);
    }
    VMCNT(0);                            // next tile landed (had whole compute)
    __builtin_amdgcn_s_barrier();
  }

  float4 cb4 = *(const float4*)(cadd + b * TTXT + sb * BN + tx * 4);
  float c0[4] = {cb4.x, cb4.y, cb4.z, cb4.w};
  size_t rowbase = (size_t)b * TFEAT * TTXT + (size_t)(tb * BM + ty * 8) * TTXT + sb * BN;
  float* ob = neg + rowbase;
  unsigned short* oh = negh + rowbase;
  #pragma unroll
  for (int i = 0; i < 8; ++i) {
    float4 o = {acc[i][0] + c0[0], acc[i][1] + c0[1], acc[i][2] + c0[2], acc[i][3] + c0[3]};
    *(float4*)(ob + (size_t)i * TTXT + tx * 4) = o;
    ushort4 h = {f2b16(o.x), f2b16(o.y), f2b16(o.z), f2b16(o.w)};
    *(ushort4*)(oh + (size_t)i * TTXT + tx * 4) = h;
  }
}

// ---------------------------------------------------------------------------
// Kernel C (R15): skewed-wavefront DP = R13's per-wave-ring structure
// (producer==consumer per wave, 4-deep ring — R14's SHARED ring raced:
// 8 windows in flight > 4 slots), staging BF16 (negh) instead of f32.
// Halves bytes AND cache lines of the per-CU stream that the ~320cy/row
// invariance points to. bf16->f32 decode = exact bit-shift; DP math form
// identical. Tail VMCNT properly counted (6/4/2/0).
// ---------------------------------------------------------------------------
#define KROWS 16
#define NWIN  (TFEAT / KROWS)     // 128 windows
#define NMASKW (TTXT / KROWS)     // 32 masked windows

__device__ __forceinline__ float dpp_shr1(float v) {
  return __int_as_float(__builtin_amdgcn_update_dpp(
      __float_as_int(v), __float_as_int(v), 0x138 /*wave_shr:1*/, 0xF, 0xF, false));
}

__global__ __launch_bounds__(512, 1)
void k_dp(const unsigned short* __restrict__ negh, float* __restrict__ dur,
          int* __restrict__ idx_out, const float* __restrict__ x_mask,
          unsigned long long* __restrict__ gbits_all) {
  __shared__ unsigned short ringh[8][4][KROWS * 64];  // 65536 B per-wave ring
  __shared__ float bndlds[3][8][KROWS];               //  1536 B boundary ring
  int b = blockIdx.x, tid = threadIdx.x;
  int lane = tid & 63, w = tid >> 6;
  const unsigned short* nb = negh + (size_t)b * TFEAT * TTXT + w * 64;
  unsigned long long* gbits = gbits_all + (size_t)b * 8 * TFEAT;  // [8][2048]

  if (tid < 3 * 8 * KROWS) ((float*)bndlds)[tid] = NEGINF;

  // per-lane gather: lane l -> slice row (l>>3), slice cols (l&7)*8..+7
  int offh = (lane >> 3) * TTXT + (lane & 7) * 8;
  auto stage = [&](int j) {               // this wave's 64-col slice, 2 x 1KB
    int slot = j & 3;
    const unsigned short* s0 = nb + (size_t)(j * KROWS) * TTXT + offh;
    gload_lds16h(s0,            &ringh[w][slot][0]);
    gload_lds16h(s0 + 8 * TTXT, &ringh[w][slot][512]);
  };

  stage(0); stage(1); stage(2);
  __syncthreads();                        // drains prologue loads + bndlds init

  float prev = NEGINF;
  for (int p = 0; p < NWIN + 8; ++p) {
    int i = p - w;                        // this wave's window this phase
    if (i >= 0 && i + 3 < NWIN) { stage(i + 3); VMCNT(6); }
    else if (i >= 0) {
      int rem = NWIN - 1 - i;
      if (rem == 2)      VMCNT(4);
      else if (rem == 1) VMCNT(2);
      else               VMCNT(0);
    }
    asm volatile("s_waitcnt lgkmcnt(0)" ::: "memory");
    __builtin_amdgcn_s_barrier();         // bndlds(prev phase) visible
    __builtin_amdgcn_sched_barrier(0);

    if (i >= 0 && i < NWIN) {
      // hoisted boundary values (wave-uniform)
      float s_bnd[KROWS];
      if (w > 0) {
        float v   = bndlds[i % 3][w - 1][lane & 15];
        float v15 = bndlds[(i + 2) % 3][w - 1][15];
        s_bnd[0] = __int_as_float(__builtin_amdgcn_readfirstlane(__float_as_int(v15)));
        #pragma unroll
        for (int r = 1; r < KROWS; ++r)
          s_bnd[r] = __int_as_float(__builtin_amdgcn_readlane(__float_as_int(v), r - 1));
      } else {
        #pragma unroll
        for (int r = 0; r < KROWS; ++r) s_bnd[r] = NEGINF;
        if (i == 0) s_bnd[0] = 0.0f;      // y==0, x==0 edge
      }
      // own-slice nf: bf16 -> f32 exact decode
      float cur[KROWS];
      #pragma unroll
      for (int r = 0; r < KROWS; ++r)
        cur[r] = __uint_as_float((unsigned)ringh[w][i & 3][r * 64 + lane] << 16);

      int y0 = i * KROWS;
      bool masked = (i < NMASKW);
      unsigned keep_lo = 0, keep_hi = 0;
      float bkeep = 0.0f;
      unsigned long long andm = (w == 0) ? ~1ull : ~0ull;   // x==0 never moves
      #pragma unroll
      for (int r = 0; r < KROWS; ++r) {
        float upd = dpp_shr1(prev);
        float up = (lane == 0) ? s_bnd[r] : upd;
        bool force = masked && (tid == y0 + r);
        bool gt = prev < up;
        unsigned long long m = __ballot(force || gt) & andm;  // uniform
        bool mine = (lane == r);
        keep_lo = mine ? (unsigned)m : keep_lo;
        keep_hi = mine ? (unsigned)(m >> 32) : keep_hi;
        float vc = force ? NEGINF : prev;
        prev = fmaxf(vc, up) + cur[r];
        float v63 = __int_as_float(
            __builtin_amdgcn_readlane(__float_as_int(prev), 63));  // uniform
        bkeep = mine ? v63 : bkeep;
      }
      if (lane < KROWS) {                 // one exec toggle per window
        bndlds[i % 3][w][lane] = bkeep;
        gbits[(size_t)w * TFEAT + y0 + lane] =
            ((unsigned long long)keep_hi << 32) | keep_lo;   // 128B contiguous
      }
    }
  }
  VMCNT(0);
  __syncthreads();                        // gbits stores drained + visible

  // ---- serial backtrack (tid 0), 16-deep register ring over global bits.
  if (tid == 0) {
    const float* xm = x_mask + (size_t)b * TTXT;
    int idx = TTXT - 1, cnt = 0;
    unsigned long long ua[16], ub[16]; int qi[16];
    #pragma unroll
    for (int q16 = 0; q16 < 16; ++q16) {  // rows 2032..2047 (slot = y&15)
      ua[q16] = gbits[(size_t)7 * TFEAT + 2032 + q16];
      ub[q16] = gbits[(size_t)6 * TFEAT + 2032 + q16];
      qi[q16] = 7;
    }
    for (int yb = 2032; yb >= 16; yb -= 16) {
      #pragma unroll
      for (int jj = 15; jj >= 0; --jj) {
        int y = yb + jj;                  // slot = jj (yb % 16 == 0)
        unsigned long long w64 = ((idx >> 6) == qi[jj]) ? ua[jj] : ub[jj];
        idx_out[b * TFEAT + y] = idx;
        cnt++;
        if ((w64 >> (idx & 63)) & 1ull) {
          dur[b * TTXT + idx] = (float)cnt * xm[idx];
          cnt = 0; idx--;
        }
        int q = idx >> 6;                 // refill slot jj for row y-16
        int qm = q > 0 ? q - 1 : 0;
        ua[jj] = gbits[(size_t)q  * TFEAT + (y - 16)];
        ub[jj] = gbits[(size_t)qm * TFEAT + (y - 16)];
        qi[jj] = q;
      }
    }
    #pragma unroll
    for (int jj = 15; jj >= 0; --jj) {    // tail rows 15..0
      int y = jj;
      unsigned long long w64 = ((idx >> 6) == qi[jj]) ? ua[jj] : ub[jj];
      idx_out[b * TFEAT + y] = idx;
      cnt++;
      if ((w64 >> (idx & 63)) & 1ull) {
        dur[b * TTXT + idx] = (float)cnt * xm[idx];
        cnt = 0; idx--;
      }
    }
    dur[b * TTXT] = (float)cnt * xm[0];   // idx == 0 tail run
  }
}

// ---------------------------------------------------------------------------
// Kernel D: attn[b,y,x] = (x == idx[y]) * x_mask[b,x] * y_mask[b,y]
// ---------------------------------------------------------------------------
__global__ void k_attn(const int* __restrict__ idx_arr,
                       const float* __restrict__ x_mask,
                       const float* __restrict__ y_mask,
                       float* __restrict__ attn) {
  size_t gid = (size_t)blockIdx.x * 256 + threadIdx.x;
  size_t e = gid << 2;               // 4 floats per thread
  int b = (int)(e >> 20);            // TFEAT*TTXT = 2^20
  int rem = (int)(e & 1048575u);
  int y = rem >> 9;
  int x0 = rem & 511;
  int idx = idx_arr[b * TFEAT + y];
  float4 v = {0.f, 0.f, 0.f, 0.f};
  int d = idx - x0;
  if (d >= 0 && d < 4) {
    ((float*)&v)[d] = x_mask[b * TTXT + idx] * y_mask[b * TFEAT + y];
  }
  *(float4*)(attn + e) = v;
}

// ---------------------------------------------------------------------------
extern "C" void kernel_launch(void* const* d_in, const int* in_sizes, int n_in,
                              void* d_out, int out_size, void* d_ws, size_t ws_size,
                              hipStream_t stream) {
  const float* z_p    = (const float*)d_in[0];
  const float* m_p    = (const float*)d_in[1];
  const float* logs_p = (const float*)d_in[2];
  const float* x_mask = (const float*)d_in[3];
  const float* y_mask = (const float*)d_in[4];

  float* out  = (float*)d_out;
  float* attn = out;
  float* dur  = out + DUR_OFF;
  float* neg  = out + NEG_OFF;

  // scratch in the attn region (fully rewritten by k_attn at the end):
  //   w1s/w2s (24MB, dead after k_gemm) | gbits (4MB) | negh (64MB bf16)
  float* w1s = attn;
  float* w2s = attn + (size_t)BATCH * CH * TTXT;          // 3,145,728 floats
  unsigned long long* gbits =
      (unsigned long long*)(attn + 2 * (size_t)BATCH * CH * TTXT);
  unsigned short* negh =
      (unsigned short*)(attn + 2 * (size_t)BATCH * CH * TTXT + 1048576);

  // workspace: cadd (64 KiB) + idx array (256 KiB)
  float* cadd = (float*)d_ws;
  int*   idxa = (int*)((char*)d_ws + 65536);

  k_prep<<<(BATCH * CH * TTXT) / 256, 256, 0, stream>>>(m_p, logs_p, w1s, w2s);
  k_cadd<<<(BATCH * TTXT) / 256, 256, 0, stream>>>(m_p, logs_p, cadd);
  k_gemm<<<BATCH * (TFEAT / BM) * (TTXT / BN), 512, 0, stream>>>(z_p, w1s, w2s, cadd, neg, negh);
  k_dp<<<BATCH, 512, 0, stream>>>(negh, dur, idxa, x_mask, gbits);
  k_attn<<<(int)(ATTN_ELEMS / 4 / 256), 256, 0, stream>>>(idxa, x_mask, y_mask, attn);
}

// Round 16
// 743.942 us; speedup vs baseline: 1.1054x; 1.0004x over previous
//
#include <hip/hip_runtime.h>
#include <math.h>

// Problem constants (fixed by the reference setup_inputs)
#define BATCH 32
#define CH    192
#define TFEAT 2048
#define TTXT  512
#define NEGINF (-1e9f)

#define ATTN_ELEMS ((size_t)BATCH * TFEAT * TTXT)   // 33,554,432
#define DUR_OFF    ATTN_ELEMS
#define NEG_OFF    (ATTN_ELEMS + (size_t)BATCH * TTXT)

__device__ __forceinline__ void gload_lds16(const float* g, float* l) {
  __builtin_amdgcn_global_load_lds(
      (const __attribute__((address_space(1))) void*)g,
      (__attribute__((address_space(3))) void*)l, 16, 0, 0);
}
__device__ __forceinline__ void gload_lds16h(const unsigned short* g,
                                             unsigned short* l) {
  __builtin_amdgcn_global_load_lds(
      (const __attribute__((address_space(1))) void*)g,
      (__attribute__((address_space(3))) void*)l, 16, 0, 0);
}

#define VMCNT(n) asm volatile("s_waitcnt vmcnt(" #n ")" ::: "memory")

__device__ __forceinline__ unsigned short f2b16(float f) {   // RNE bf16
  unsigned u = __float_as_uint(f);
  return (unsigned short)((u + 0x7FFFu + ((u >> 16) & 1u)) >> 16);
}

// ---------------------------------------------------------------------------
// Kernel P: W1[b,c,s] = m*exp(-2*logs), W2[b,c,s] = -0.5*exp(-2*logs)
// ---------------------------------------------------------------------------
__global__ void k_prep(const float* __restrict__ m_p,
                       const float* __restrict__ logs_p,
                       float* __restrict__ w1, float* __restrict__ w2) {
  int gid = blockIdx.x * 256 + threadIdx.x;    // 0 .. 3,145,727
  float m = m_p[gid];
  float l = logs_p[gid];
  float r = __expf(-2.0f * l);
  w1[gid] = m * r;
  w2[gid] = -0.5f * r;
}

// ---------------------------------------------------------------------------
// Kernel A: cadd[b][s] = sum_c(-0.5*log(2pi) - logs) + sum_c(-0.5*m^2*r)
// ---------------------------------------------------------------------------
__global__ void k_cadd(const float* __restrict__ m_p,
                       const float* __restrict__ logs_p,
                       float* __restrict__ cadd) {
  int gid = blockIdx.x * 256 + threadIdx.x;        // 0 .. 16383
  int b = gid >> 9, s = gid & (TTXT - 1);
  const float* mp = m_p    + (size_t)b * CH * TTXT + s;
  const float* lp = logs_p + (size_t)b * CH * TTXT + s;
  float acc = -0.5f * 1.8378770664093453f * (float)CH;   // -C/2 * log(2*pi)
  #pragma unroll 4
  for (int c = 0; c < CH; ++c) {
    float l = lp[(size_t)c * TTXT];
    float m = mp[(size_t)c * TTXT];
    float r = __expf(-2.0f * l);
    acc -= l + 0.5f * m * m * r;
  }
  cadd[gid] = acc;
}

// ---------------------------------------------------------------------------
// Kernel B: fp32 GEMM (R13 structure: 512 thr, acc[8][4], Frag depth-1
// pipeline, 2-phase LDS dbuf; VGPR 116, zero spill). R16 change: the bf16
// shadow negh is written RE-TILED so each k_dp wave's 2KB window-slice is
// contiguous: negh[((b*128+iw)*8 + w)*1024 + r*64 + c], iw=row>>4,
// w=col>>6, r=row&15, c=col&63. f32 neg output unchanged.
// ---------------------------------------------------------------------------
#define BM 128
#define BN 128
#define BK 16

struct Frag { float a[8]; float p[4]; float q[4]; };

__global__ __launch_bounds__(512)
void k_gemm(const float* __restrict__ z_p,
            const float* __restrict__ w1g, const float* __restrict__ w2g,
            const float* __restrict__ cadd, float* __restrict__ neg,
            unsigned short* __restrict__ negh) {
  __shared__ float Az[2][BK][BM];
  __shared__ float B1[2][BK][BN];
  __shared__ float B2[2][BK][BN];

  // chunked XCD swizzle (2048 blocks, 8 XCDs, 256 per chunk; bijective)
  int blk = (blockIdx.x & 7) * 256 + (blockIdx.x >> 3);
  int sb = blk & 3;            // TTXT/BN = 4
  int tb = (blk >> 2) & 15;    // TFEAT/BM = 16
  int b  = blk >> 6;
  int tid = threadIdx.x;
  int tx = tid & 31;           // col group: 4 cols at tx*4
  int ty = tid >> 5;           // row group: 8 rows at ty*8  (0..15)
  int wid  = tid >> 6;         // wave 0..7
  int lane = tid & 63;
  int lr = lane >> 5;          // row-within-pair
  int lc = (lane & 31) * 4;    // col (float4 granularity)

  const float* zb  = z_p + (size_t)b * CH * TFEAT + (size_t)tb * BM;
  const float* w1b = w1g + (size_t)b * CH * TTXT  + (size_t)sb * BN;
  const float* w2b = w2g + (size_t)b * CH * TTXT  + (size_t)sb * BN;

  auto STAGE = [&](int buf, int ko) {
    int kr = ko * BK + 2 * wid + lr;     // per-lane global k-row
    int kd = 2 * wid;                    // wave-uniform LDS row base
    gload_lds16(zb  + (size_t)kr * TFEAT + lc, &Az[buf][kd][0]);
    gload_lds16(w1b + (size_t)kr * TTXT  + lc, &B1[buf][kd][0]);
    gload_lds16(w2b + (size_t)kr * TTXT  + lc, &B2[buf][kd][0]);
  };
  auto LOADF = [&](Frag& f, int cur, int kk) {
    float4 a0 = *(const float4*)&Az[cur][kk][ty * 8];
    float4 a1 = *(const float4*)&Az[cur][kk][ty * 8 + 4];
    float4 p  = *(const float4*)&B1[cur][kk][tx * 4];
    float4 q  = *(const float4*)&B2[cur][kk][tx * 4];
    f.a[0]=a0.x; f.a[1]=a0.y; f.a[2]=a0.z; f.a[3]=a0.w;
    f.a[4]=a1.x; f.a[5]=a1.y; f.a[6]=a1.z; f.a[7]=a1.w;
    f.p[0]=p.x;  f.p[1]=p.y;  f.p[2]=p.z;  f.p[3]=p.w;
    f.q[0]=q.x;  f.q[1]=q.y;  f.q[2]=q.z;  f.q[3]=q.w;
  };

  float acc[8][4];
  #pragma unroll
  for (int i = 0; i < 8; ++i)
    #pragma unroll
    for (int j = 0; j < 4; ++j) acc[i][j] = 0.0f;

  auto FMAF = [&](const Frag& f) {
    #pragma unroll
    for (int i = 0; i < 8; ++i)
      #pragma unroll
      for (int j = 0; j < 4; ++j)
        acc[i][j] = fmaf(f.a[i], fmaf(f.a[i], f.q[j], f.p[j]), acc[i][j]);
  };

  STAGE(0, 0);
  VMCNT(0);
  __builtin_amdgcn_s_barrier();

  for (int ko = 0; ko < CH / BK; ++ko) {
    int cur = ko & 1;
    if (ko + 1 < CH / BK) STAGE(cur ^ 1, ko + 1);   // prefetch next tile

    Frag f0, f1;
    LOADF(f0, cur, 0);
    #pragma unroll
    for (int kk = 0; kk < BK; kk += 2) {
      LOADF(f1, cur, kk + 1);            // reads hide under FMAF(f0)
      FMAF(f0);
      __builtin_amdgcn_sched_barrier(0);
      if (kk + 2 < BK) LOADF(f0, cur, kk + 2);
      FMAF(f1);
      __builtin_amdgcn_sched_barrier(0);
    }
    VMCNT(0);                            // next tile landed (had whole compute)
    __builtin_amdgcn_s_barrier();
  }

  float4 cb4 = *(const float4*)(cadd + b * TTXT + sb * BN + tx * 4);
  float c0[4] = {cb4.x, cb4.y, cb4.z, cb4.w};
  float* ob = neg + (size_t)b * TFEAT * TTXT
            + (size_t)(tb * BM + ty * 8) * TTXT + sb * BN;
  // re-tiled bf16 shadow destination (see header comment)
  unsigned short* oh = negh
      + (((size_t)b * 128 + tb * 8 + (ty >> 1)) * 8 + 2 * sb + (tx >> 4)) * 1024
      + (size_t)((ty & 1) * 8) * 64 + (tx & 15) * 4;
  #pragma unroll
  for (int i = 0; i < 8; ++i) {
    float4 o = {acc[i][0] + c0[0], acc[i][1] + c0[1], acc[i][2] + c0[2], acc[i][3] + c0[3]};
    *(float4*)(ob + (size_t)i * TTXT + tx * 4) = o;
    ushort4 h = {f2b16(o.x), f2b16(o.y), f2b16(o.z), f2b16(o.w)};
    *(ushort4*)(oh + (size_t)i * 64) = h;
  }
}

// ---------------------------------------------------------------------------
// Kernel C (R16): skewed-wavefront DP, per-wave ring (race-free), staging
// from the RE-TILED bf16 negh: each wave's window slice = one contiguous
// 2KB block -> 2 contiguous 1KB gload_lds = 2 segments/window/wave
// (16/phase vs R13/R15's 128). Segment model predicts ~175us.
// Ring/consumer/math verbatim R15 -> bit-exact path.
// ---------------------------------------------------------------------------
#define KROWS 16
#define NWIN  (TFEAT / KROWS)     // 128 windows
#define NMASKW (TTXT / KROWS)     // 32 masked windows

__device__ __forceinline__ float dpp_shr1(float v) {
  return __int_as_float(__builtin_amdgcn_update_dpp(
      __float_as_int(v), __float_as_int(v), 0x138 /*wave_shr:1*/, 0xF, 0xF, false));
}

__global__ __launch_bounds__(512, 1)
void k_dp(const unsigned short* __restrict__ negh, float* __restrict__ dur,
          int* __restrict__ idx_out, const float* __restrict__ x_mask,
          unsigned long long* __restrict__ gbits_all) {
  __shared__ unsigned short ringh[8][4][KROWS * 64];  // 65536 B per-wave ring
  __shared__ float bndlds[3][8][KROWS];               //  1536 B boundary ring
  int b = blockIdx.x, tid = threadIdx.x;
  int lane = tid & 63, w = tid >> 6;
  // wave w's slice stream: blocks of 1024 ushorts per (window, wave)
  const unsigned short* nb =
      negh + (((size_t)b * NWIN) * 8 + w) * 1024 + lane * 8;
  unsigned long long* gbits = gbits_all + (size_t)b * 8 * TFEAT;  // [8][2048]

  if (tid < 3 * 8 * KROWS) ((float*)bndlds)[tid] = NEGINF;

  auto stage = [&](int j) {               // 2 contiguous 1KB loads
    int slot = j & 3;
    const unsigned short* s0 = nb + (size_t)j * 8 * 1024;
    gload_lds16h(s0,       &ringh[w][slot][0]);
    gload_lds16h(s0 + 512, &ringh[w][slot][512]);
  };

  stage(0); stage(1); stage(2);
  __syncthreads();                        // drains prologue loads + bndlds init

  float prev = NEGINF;
  for (int p = 0; p < NWIN + 8; ++p) {
    int i = p - w;                        // this wave's window this phase
    if (i >= 0 && i + 3 < NWIN) { stage(i + 3); VMCNT(6); }
    else if (i >= 0) {
      int rem = NWIN - 1 - i;
      if (rem == 2)      VMCNT(4);
      else if (rem == 1) VMCNT(2);
      else               VMCNT(0);
    }
    asm volatile("s_waitcnt lgkmcnt(0)" ::: "memory");
    __builtin_amdgcn_s_barrier();         // bndlds(prev phase) visible
    __builtin_amdgcn_sched_barrier(0);

    if (i >= 0 && i < NWIN) {
      // hoisted boundary values (wave-uniform)
      float s_bnd[KROWS];
      if (w > 0) {
        float v   = bndlds[i % 3][w - 1][lane & 15];
        float v15 = bndlds[(i + 2) % 3][w - 1][15];
        s_bnd[0] = __int_as_float(__builtin_amdgcn_readfirstlane(__float_as_int(v15)));
        #pragma unroll
        for (int r = 1; r < KROWS; ++r)
          s_bnd[r] = __int_as_float(__builtin_amdgcn_readlane(__float_as_int(v), r - 1));
      } else {
        #pragma unroll
        for (int r = 0; r < KROWS; ++r) s_bnd[r] = NEGINF;
        if (i == 0) s_bnd[0] = 0.0f;      // y==0, x==0 edge
      }
      // own-slice nf: bf16 -> f32 exact decode
      float cur[KROWS];
      #pragma unroll
      for (int r = 0; r < KROWS; ++r)
        cur[r] = __uint_as_float((unsigned)ringh[w][i & 3][r * 64 + lane] << 16);

      int y0 = i * KROWS;
      bool masked = (i < NMASKW);
      unsigned keep_lo = 0, keep_hi = 0;
      float bkeep = 0.0f;
      unsigned long long andm = (w == 0) ? ~1ull : ~0ull;   // x==0 never moves
      #pragma unroll
      for (int r = 0; r < KROWS; ++r) {
        float upd = dpp_shr1(prev);
        float up = (lane == 0) ? s_bnd[r] : upd;
        bool force = masked && (tid == y0 + r);
        bool gt = prev < up;
        unsigned long long m = __ballot(force || gt) & andm;  // uniform
        bool mine = (lane == r);
        keep_lo = mine ? (unsigned)m : keep_lo;
        keep_hi = mine ? (unsigned)(m >> 32) : keep_hi;
        float vc = force ? NEGINF : prev;
        prev = fmaxf(vc, up) + cur[r];
        float v63 = __int_as_float(
            __builtin_amdgcn_readlane(__float_as_int(prev), 63));  // uniform
        bkeep = mine ? v63 : bkeep;
      }
      if (lane < KROWS) {                 // one exec toggle per window
        bndlds[i % 3][w][lane] = bkeep;
        gbits[(size_t)w * TFEAT + y0 + lane] =
            ((unsigned long long)keep_hi << 32) | keep_lo;   // 128B contiguous
      }
    }
  }
  VMCNT(0);
  __syncthreads();                        // gbits stores drained + visible

  // ---- serial backtrack (tid 0), 16-deep register ring over global bits.
  if (tid == 0) {
    const float* xm = x_mask + (size_t)b * TTXT;
    int idx = TTXT - 1, cnt = 0;
    unsigned long long ua[16], ub[16]; int qi[16];
    #pragma unroll
    for (int q16 = 0; q16 < 16; ++q16) {  // rows 2032..2047 (slot = y&15)
      ua[q16] = gbits[(size_t)7 * TFEAT + 2032 + q16];
      ub[q16] = gbits[(size_t)6 * TFEAT + 2032 + q16];
      qi[q16] = 7;
    }
    for (int yb = 2032; yb >= 16; yb -= 16) {
      #pragma unroll
      for (int jj = 15; jj >= 0; --jj) {
        int y = yb + jj;                  // slot = jj (yb % 16 == 0)
        unsigned long long w64 = ((idx >> 6) == qi[jj]) ? ua[jj] : ub[jj];
        idx_out[b * TFEAT + y] = idx;
        cnt++;
        if ((w64 >> (idx & 63)) & 1ull) {
          dur[b * TTXT + idx] = (float)cnt * xm[idx];
          cnt = 0; idx--;
        }
        int q = idx >> 6;                 // refill slot jj for row y-16
        int qm = q > 0 ? q - 1 : 0;
        ua[jj] = gbits[(size_t)q  * TFEAT + (y - 16)];
        ub[jj] = gbits[(size_t)qm * TFEAT + (y - 16)];
        qi[jj] = q;
      }
    }
    #pragma unroll
    for (int jj = 15; jj >= 0; --jj) {    // tail rows 15..0
      int y = jj;
      unsigned long long w64 = ((idx >> 6) == qi[jj]) ? ua[jj] : ub[jj];
      idx_out[b * TFEAT + y] = idx;
      cnt++;
      if ((w64 >> (idx & 63)) & 1ull) {
        dur[b * TTXT + idx] = (float)cnt * xm[idx];
        cnt = 0; idx--;
      }
    }
    dur[b * TTXT] = (float)cnt * xm[0];   // idx == 0 tail run
  }
}

// ---------------------------------------------------------------------------
// Kernel D: attn[b,y,x] = (x == idx[y]) * x_mask[b,x] * y_mask[b,y]
// ---------------------------------------------------------------------------
__global__ void k_attn(const int* __restrict__ idx_arr,
                       const float* __restrict__ x_mask,
                       const float* __restrict__ y_mask,
                       float* __restrict__ attn) {
  size_t gid = (size_t)blockIdx.x * 256 + threadIdx.x;
  size_t e = gid << 2;               // 4 floats per thread
  int b = (int)(e >> 20);            // TFEAT*TTXT = 2^20
  int rem = (int)(e & 1048575u);
  int y = rem >> 9;
  int x0 = rem & 511;
  int idx = idx_arr[b * TFEAT + y];
  float4 v = {0.f, 0.f, 0.f, 0.f};
  int d = idx - x0;
  if (d >= 0 && d < 4) {
    ((float*)&v)[d] = x_mask[b * TTXT + idx] * y_mask[b * TFEAT + y];
  }
  *(float4*)(attn + e) = v;
}

// ---------------------------------------------------------------------------
extern "C" void kernel_launch(void* const* d_in, const int* in_sizes, int n_in,
                              void* d_out, int out_size, void* d_ws, size_t ws_size,
                              hipStream_t stream) {
  const float* z_p    = (const float*)d_in[0];
  const float* m_p    = (const float*)d_in[1];
  const float* logs_p = (const float*)d_in[2];
  const float* x_mask = (const float*)d_in[3];
  const float* y_mask = (const float*)d_in[4];

  float* out  = (float*)d_out;
  float* attn = out;
  float* dur  = out + DUR_OFF;
  float* neg  = out + NEG_OFF;

  // scratch in the attn region (fully rewritten by k_attn at the end):
  //   w1s/w2s (24MB, dead after k_gemm) | gbits (4MB) | negh (64MB bf16)
  float* w1s = attn;
  float* w2s = attn + (size_t)BATCH * CH * TTXT;          // 3,145,728 floats
  unsigned long long* gbits =
      (unsigned long long*)(attn + 2 * (size_t)BATCH * CH * TTXT);
  unsigned short* negh =
      (unsigned short*)(attn + 2 * (size_t)BATCH * CH * TTXT + 1048576);

  // workspace: cadd (64 KiB) + idx array (256 KiB)
  float* cadd = (float*)d_ws;
  int*   idxa = (int*)((char*)d_ws + 65536);

  k_prep<<<(BATCH * CH * TTXT) / 256, 256, 0, stream>>>(m_p, logs_p, w1s, w2s);
  k_cadd<<<(BATCH * TTXT) / 256, 256, 0, stream>>>(m_p, logs_p, cadd);
  k_gemm<<<BATCH * (TFEAT / BM) * (TTXT / BN), 512, 0, stream>>>(z_p, w1s, w2s, cadd, neg, negh);
  k_dp<<<BATCH, 512, 0, stream>>>(negh, dur, idxa, x_mask, gbits);
  k_attn<<<(int)(ATTN_ELEMS / 4 / 256), 256, 0, stream>>>(idxa, x_mask, y_mask, attn);
}